// Round 1
// baseline (777.260 us; speedup 1.0000x reference)
//
#include <hip/hip_runtime.h>
#include <hip/hip_bf16.h>

#define D 64

// ---------------- int64-vs-int32 edge_index detection ----------------
__global__ void detect_kernel(const unsigned int* e32, int* flag) {
    __shared__ int nz;
    if (threadIdx.x == 0) nz = 0;
    __syncthreads();
    // If stored as int64 (values < 2^31), every high word is 0.
    if (e32[2 * threadIdx.x + 1] != 0) nz = 1;
    __syncthreads();
    if (threadIdx.x == 0) *flag = (nz == 0) ? 1 : 0;
}

__device__ __forceinline__ int load_idx(const void* e, int is64, long long i) {
    if (is64) return (int)((const long long*)e)[i];
    return ((const int*)e)[i];
}

// ---------------- degree histogram ----------------
__global__ void deg_count_kernel(const void* edges, const int* flag, int* degi, int E) {
    int e = blockIdx.x * 256 + threadIdx.x;
    if (e >= E) return;
    int is64 = *flag;
    int dst = load_idx(edges, is64, (long long)E + e);
    atomicAdd(&degi[dst], 1);
}

__global__ void dinv_kernel(const int* degi, float* dinv, int n) {
    int v = blockIdx.x * 256 + threadIdx.x;
    if (v >= n) return;
    // deg includes self-loop: degi (edge-only) + 1  -> always >= 1
    dinv[v] = rsqrtf((float)(degi[v] + 1));
}

// ---------------- exclusive scan (3 kernels, 1024-wide blocks) ----------------
__global__ __launch_bounds__(1024) void scanA_kernel(const int* deg, int* offs, int* bsums, int n) {
    __shared__ int s[1024];
    int tid = threadIdx.x;
    int i = blockIdx.x * 1024 + tid;
    int v = (i < n) ? deg[i] : 0;
    s[tid] = v;
    __syncthreads();
    for (int d = 1; d < 1024; d <<= 1) {
        int t = (tid >= d) ? s[tid - d] : 0;
        __syncthreads();
        s[tid] += t;
        __syncthreads();
    }
    if (i < n) offs[i] = s[tid] - v;  // exclusive
    if (tid == 1023) bsums[blockIdx.x] = s[1023];
}

__global__ __launch_bounds__(1024) void scanB_kernel(int* bsums, int nb) {
    __shared__ int s[1024];
    int tid = threadIdx.x;
    int v = (tid < nb) ? bsums[tid] : 0;
    s[tid] = v;
    __syncthreads();
    for (int d = 1; d < 1024; d <<= 1) {
        int t = (tid >= d) ? s[tid - d] : 0;
        __syncthreads();
        s[tid] += t;
        __syncthreads();
    }
    if (tid < nb) bsums[tid] = s[tid] - v;  // exclusive block offsets
}

__global__ __launch_bounds__(1024) void scanC_kernel(int* offs, const int* bsums, int* fillptr,
                                                     int n, int E) {
    int i = blockIdx.x * 1024 + threadIdx.x;
    if (i < n) {
        int o = offs[i] + bsums[blockIdx.x];
        offs[i] = o;
        fillptr[i] = o;
    }
    if (i == 0) offs[n] = E;
}

// ---------------- CSR fill ----------------
__global__ void fill_kernel(const void* edges, const int* flag, const float* dinv,
                            int* fillptr, int* srcs, float* norms, int E) {
    int e = blockIdx.x * 256 + threadIdx.x;
    if (e >= E) return;
    int is64 = *flag;
    int s = load_idx(edges, is64, e);
    int d = load_idx(edges, is64, (long long)E + e);
    int pos = atomicAdd(&fillptr[d], 1);
    srcs[pos] = s;
    norms[pos] = dinv[s] * dinv[d];
}

// ---------------- dense [n,64] @ [64,64] matmul ----------------
__global__ __launch_bounds__(256) void mm64_kernel(const float* __restrict__ X,
                                                   const float* __restrict__ W,
                                                   float* __restrict__ Y, int n) {
    __shared__ float Wl[64 * 64];
    __shared__ float Xl[256];
    for (int i = threadIdx.x; i < 64 * 64; i += 256) Wl[i] = W[i];
    int c = threadIdx.x & 63;
    int r = threadIdx.x >> 6;
    int ngrp = (n + 3) >> 2;
    for (int g = blockIdx.x; g < ngrp; g += gridDim.x) {
        __syncthreads();  // protects Xl from previous iter + Wl on first iter
        int li = g * 256 + (int)threadIdx.x;
        Xl[threadIdx.x] = (li < n * 64) ? X[li] : 0.f;
        __syncthreads();
        int row = g * 4 + r;
        if (row < n) {
            float acc = 0.f;
#pragma unroll
            for (int k = 0; k < 64; k++) acc += Xl[(r << 6) + k] * Wl[(k << 6) + c];
            Y[row * 64 + c] = acc;
        }
    }
}

// ---------------- aggregation: one wave per dst node, lane = feature ----------------
__global__ __launch_bounds__(256) void agg_kernel(const float* __restrict__ T,
                                                  const int* __restrict__ offs,
                                                  const int* __restrict__ srcs,
                                                  const float* __restrict__ norms,
                                                  const float* __restrict__ dinv,
                                                  const float* __restrict__ bias,
                                                  float* __restrict__ out, int n) {
    int v = blockIdx.x * 4 + (threadIdx.x >> 6);
    if (v >= n) return;
    int lane = threadIdx.x & 63;
    float di = dinv[v];
    float acc = di * di * T[(long long)v * D + lane];  // self-loop
    int j0 = offs[v], j1 = offs[v + 1];
    for (int j = j0; j < j1; j++) {
        int s = srcs[j];
        float nm = norms[j];
        acc += nm * T[(long long)s * D + lane];
    }
    out[(long long)v * D + lane] = acc + bias[lane];
}

// ---------------- batchnorm ----------------
__global__ __launch_bounds__(256) void bnstats_kernel(const float* __restrict__ H,
                                                      float* __restrict__ stats, int n) {
    int f = threadIdx.x & 63;
    int r = threadIdx.x >> 6;
    float s = 0.f, q = 0.f;
    for (int node = blockIdx.x * 4 + r; node < n; node += gridDim.x * 4) {
        float x = H[(long long)node * D + f];
        s += x;
        q += x * x;
    }
    __shared__ float ls[256], lq[256];
    ls[threadIdx.x] = s;
    lq[threadIdx.x] = q;
    __syncthreads();
    if (r == 0) {
        s = ls[f] + ls[64 + f] + ls[128 + f] + ls[192 + f];
        q = lq[f] + lq[64 + f] + lq[128 + f] + lq[192 + f];
        atomicAdd(&stats[f], s);
        atomicAdd(&stats[64 + f], q);
    }
}

__global__ __launch_bounds__(256) void bnapply_kernel(float* __restrict__ H,
                                                      const float* __restrict__ stats,
                                                      const float* __restrict__ gamma,
                                                      const float* __restrict__ beta, int n) {
    long long idx = (long long)blockIdx.x * 256 + threadIdx.x;
    long long total = (long long)n * D;
    if (idx >= total) return;
    int f = (int)(idx & 63);
    float invn = 1.f / (float)n;
    float m = stats[f] * invn;
    float var = stats[64 + f] * invn - m * m;
    float x = (H[idx] - m) * rsqrtf(var + 1e-5f) * gamma[f] + beta[f];
    H[idx] = x > 0.f ? x : 0.f;
}

// ---------------- host ----------------
extern "C" void kernel_launch(void* const* d_in, const int* in_sizes, int n_in,
                              void* d_out, int out_size, void* d_ws, size_t ws_size,
                              hipStream_t stream) {
    const float* x = (const float*)d_in[0];
    const void* edges = d_in[1];
    const float* W1 = (const float*)d_in[3];
    const float* b1 = (const float*)d_in[4];
    const float* gamma1 = (const float*)d_in[5];
    const float* beta1 = (const float*)d_in[6];
    const float* W2 = (const float*)d_in[7];
    const float* b2 = (const float*)d_in[8];
    const float* gamma2 = (const float*)d_in[9];
    const float* beta2 = (const float*)d_in[10];
    const float* W3 = (const float*)d_in[11];
    const float* b3 = (const float*)d_in[12];

    const int N = in_sizes[0] / D;
    const int E = in_sizes[1] / 2;

    // workspace layout (256B aligned)
    char* ws = (char*)d_ws;
    size_t off = 0;
    auto alloc = [&](size_t bytes) -> void* {
        void* p = ws + off;
        off = (off + bytes + 255) & ~(size_t)255;
        return p;
    };
    float* dinv   = (float*)alloc((size_t)N * 4);
    int*   degi   = (int*)  alloc((size_t)N * 4);
    int*   offs   = (int*)  alloc((size_t)(N + 1) * 4);
    int*   fillp  = (int*)  alloc((size_t)N * 4);
    int*   srcs   = (int*)  alloc((size_t)E * 4);
    float* norms  = (float*)alloc((size_t)E * 4);
    int*   bsums  = (int*)  alloc(1024 * 4);
    int*   flag   = (int*)  alloc(4);
    float* stats  = (float*)alloc(128 * 4);
    float* bufA   = (float*)alloc((size_t)N * D * 4);
    float* hbuf   = (float*)d_out;  // ping-pong post-aggregation buffer; fully overwritten

    const int eb = (E + 255) / 256;
    const int nb256 = (N + 255) / 256;
    const int nb1024 = (N + 1023) / 1024;
    const int aggb = (N + 3) / 4;
    const int bnab = (int)(((long long)N * D + 255) / 256);

    // ---- build graph structure (once per call, reused for 3 layers) ----
    hipMemsetAsync(degi, 0, (size_t)N * 4, stream);
    detect_kernel<<<1, 256, 0, stream>>>((const unsigned int*)edges, flag);
    deg_count_kernel<<<eb, 256, 0, stream>>>(edges, flag, degi, E);
    dinv_kernel<<<nb256, 256, 0, stream>>>(degi, dinv, N);
    scanA_kernel<<<nb1024, 1024, 0, stream>>>(degi, offs, bsums, N);
    scanB_kernel<<<1, 1024, 0, stream>>>(bsums, nb1024);
    scanC_kernel<<<nb1024, 1024, 0, stream>>>(offs, bsums, fillp, N, E);
    fill_kernel<<<eb, 256, 0, stream>>>(edges, flag, dinv, fillp, srcs, norms, E);

    // ---- layer 1 ----
    mm64_kernel<<<1024, 256, 0, stream>>>(x, W1, bufA, N);
    agg_kernel<<<aggb, 256, 0, stream>>>(bufA, offs, srcs, norms, dinv, b1, hbuf, N);
    hipMemsetAsync(stats, 0, 128 * 4, stream);
    bnstats_kernel<<<512, 256, 0, stream>>>(hbuf, stats, N);
    bnapply_kernel<<<bnab, 256, 0, stream>>>(hbuf, stats, gamma1, beta1, N);

    // ---- layer 2 ----
    mm64_kernel<<<1024, 256, 0, stream>>>(hbuf, W2, bufA, N);
    agg_kernel<<<aggb, 256, 0, stream>>>(bufA, offs, srcs, norms, dinv, b2, hbuf, N);
    hipMemsetAsync(stats, 0, 128 * 4, stream);
    bnstats_kernel<<<512, 256, 0, stream>>>(hbuf, stats, N);
    bnapply_kernel<<<bnab, 256, 0, stream>>>(hbuf, stats, gamma2, beta2, N);

    // ---- layer 3 (no BN/ReLU) ----
    mm64_kernel<<<1024, 256, 0, stream>>>(hbuf, W3, bufA, N);
    agg_kernel<<<aggb, 256, 0, stream>>>(bufA, offs, srcs, norms, dinv, b3, (float*)d_out, N);
}